// Round 2
// baseline (449.068 us; speedup 1.0000x reference)
//
#include <hip/hip_runtime.h>
#include <stdint.h>

#define NSCENE 16
#define NPED 32
#define HD 64
#define ED 64
#define D1 8192
#define BOTN 1024

typedef unsigned short ushort_t;
typedef __attribute__((ext_vector_type(4))) float f32x4;
typedef __attribute__((ext_vector_type(8))) __bf16 bf16x8;  // gfx950 mfma operand
typedef __attribute__((ext_vector_type(4))) unsigned int u32x4;
typedef __attribute__((ext_vector_type(2))) unsigned int u32x2;

__device__ __forceinline__ float bf2f(ushort_t u) {
  union { unsigned int i; float f; } x;
  x.i = ((unsigned int)u) << 16;
  return x.f;
}

__device__ __forceinline__ ushort_t f2bf(float f) {
  union { float f; unsigned int i; } x;
  x.f = f;
  unsigned int u = x.i + 0x7fffu + ((x.i >> 16) & 1u);
  return (ushort_t)(u >> 16);
}

// pack two f32 -> two bf16 RNE (lo in bits [15:0])
__device__ __forceinline__ unsigned int packbf(float lo, float hi) {
#if __has_builtin(__builtin_amdgcn_cvt_pk_bf16_f32)
  typedef __attribute__((ext_vector_type(2))) __bf16 bf16x2_t;
  union { bf16x2_t v; unsigned int u; } x;
  x.v = __builtin_amdgcn_cvt_pk_bf16_f32(lo, hi);
  return x.u;
#else
  return (unsigned int)f2bf(lo) | ((unsigned int)f2bf(hi) << 16);
#endif
}

// unpack u32 holding 2 bf16 -> 2 f32
__device__ __forceinline__ void unpk(unsigned int u, float& lo, float& hi) {
  union { unsigned int i; float f; } a, b;
  a.i = u << 16;
  b.i = u & 0xffff0000u;
  lo = a.f;
  hi = b.f;
}

__device__ __forceinline__ float clip1(float x) {
  return fminf(fmaxf(x, -1.f), 1.f);
}

// async global->LDS DMA, 16B/lane; LDS dest = wave-uniform base + lane*16.
__device__ __forceinline__ void async_load16(const void* g, void* l) {
  __builtin_amdgcn_global_load_lds(
      (const __attribute__((address_space(1))) unsigned int*)(unsigned long long)g,
      (__attribute__((address_space(3))) unsigned int*)(unsigned int)(unsigned long long)l,
      16, 0, 0);
}

// ---------------------------------------------------------------------------
// k_pre: ALL preprocessing in one kernel of independent blocks. (unchanged)
// ---------------------------------------------------------------------------
__global__ __launch_bounds__(256) void k_pre(
    const void* __restrict__ hv_, const void* __restrict__ end_posv,
    const void* __restrict__ W_spv, const void* __restrict__ b_spv,
    const void* __restrict__ W1v, const void* __restrict__ b1v,
    const void* __restrict__ W2v, const void* __restrict__ b2v,
    int* __restrict__ flag, float* __restrict__ epf, float* __restrict__ b2f,
    float* __restrict__ M0, float* __restrict__ M1,
    ushort_t* __restrict__ hcb, ushort_t* __restrict__ W2T) {
  __shared__ ushort_t tile[64][72];
  __shared__ int cnt[256];
  __shared__ int isbf_sh;
  const int t = threadIdx.x;
  const int bid = blockIdx.x;

  // ---- inline dtype detection ----
  {
    const ushort_t* wu = (const ushort_t*)W1v;
    unsigned int u = wu[2 * t];
    int e = (u >> 7) & 0xff;
    cnt[t] = (e >= 90 && e <= 140) ? 1 : 0;
    __syncthreads();
    for (int ofs = 128; ofs > 0; ofs >>= 1) {
      if (t < ofs) cnt[t] += cnt[t + ofs];
      __syncthreads();
    }
    if (t == 0) isbf_sh = (cnt[0] >= 128) ? 1 : 0;
    __syncthreads();
  }
  const int isbf = isbf_sh;

  if (bid < 256) {
    // ================= hc: hcb[j][k] = hbias[k] + h[j]@W1[64:] =============
    const int kb = bid & 7, jt = bid >> 3;
    const int kbase = kb * 1024 + t * 4;
    float hb0, hb1, hb2, hb3;
    if (isbf) {
      const ushort_t* b1u = (const ushort_t*)b1v;
      const ushort_t* bspu = (const ushort_t*)b_spv;
      const ushort_t* wp = (const ushort_t*)W1v + kbase;
      hb0 = bf2f(b1u[kbase]); hb1 = bf2f(b1u[kbase + 1]);
      hb2 = bf2f(b1u[kbase + 2]); hb3 = bf2f(b1u[kbase + 3]);
      for (int e = 0; e < ED; ++e) {
        float bs = bf2f(bspu[e]);
        u32x2 wv = *(const u32x2*)(wp + (size_t)e * D1);
        float w0, w1, w2, w3;
        unpk(wv.x, w0, w1); unpk(wv.y, w2, w3);
        hb0 += bs * w0; hb1 += bs * w1; hb2 += bs * w2; hb3 += bs * w3;
      }
    } else {
      const float* b1f = (const float*)b1v;
      const float* bspf = (const float*)b_spv;
      const float* wp = (const float*)W1v + kbase;
      hb0 = b1f[kbase]; hb1 = b1f[kbase + 1];
      hb2 = b1f[kbase + 2]; hb3 = b1f[kbase + 3];
      for (int e = 0; e < ED; ++e) {
        float bs = bspf[e];
        float4 w = *(const float4*)(wp + (size_t)e * D1);
        hb0 += bs * w.x; hb1 += bs * w.y; hb2 += bs * w.z; hb3 += bs * w.w;
      }
    }
    float acc[16][4];
#pragma unroll
    for (int j = 0; j < 16; ++j)
#pragma unroll
      for (int c = 0; c < 4; ++c) acc[j][c] = 0.f;
    if (isbf) {
      const ushort_t* wp = (const ushort_t*)W1v + (size_t)ED * D1 + kbase;
      const ushort_t* hp = (const ushort_t*)hv_ + jt * 16 * HD;
      for (int hh = 0; hh < HD; ++hh) {
        u32x2 wv = *(const u32x2*)(wp + (size_t)hh * D1);
        float w0, w1, w2, w3;
        unpk(wv.x, w0, w1); unpk(wv.y, w2, w3);
#pragma unroll
        for (int j = 0; j < 16; ++j) {
          float hj = bf2f(hp[j * HD + hh]);
          acc[j][0] += hj * w0;
          acc[j][1] += hj * w1;
          acc[j][2] += hj * w2;
          acc[j][3] += hj * w3;
        }
      }
    } else {
      const float* wp = (const float*)W1v + (size_t)ED * D1 + kbase;
      const float* hp = (const float*)hv_ + jt * 16 * HD;
#pragma unroll 4
      for (int hh = 0; hh < HD; ++hh) {
        float4 w = *(const float4*)(wp + (size_t)hh * D1);
#pragma unroll
        for (int j = 0; j < 16; ++j) {
          float hj = hp[j * HD + hh];
          acc[j][0] += hj * w.x;
          acc[j][1] += hj * w.y;
          acc[j][2] += hj * w.z;
          acc[j][3] += hj * w.w;
        }
      }
    }
#pragma unroll
    for (int j = 0; j < 16; ++j) {
      u32x2 pk;
      pk.x = packbf(acc[j][0] + hb0, acc[j][1] + hb1);
      pk.y = packbf(acc[j][2] + hb2, acc[j][3] + hb3);
      *(u32x2*)(hcb + (size_t)(jt * 16 + j) * D1 + kbase) = pk;
    }
  } else if (bid < 2304) {
    // ================= W2 transpose =================
    const int idx = bid - 256;
    const int kt = idx & 127, nt = idx >> 7;
    const int r = t >> 3, c8 = (t & 7) * 8;
#pragma unroll
    for (int i = 0; i < 2; ++i) {
      int row = i * 32 + r;
      size_t base = (size_t)(kt * 64 + row) * BOTN + nt * 64 + c8;
      if (isbf) {
        u32x4 v = *(const u32x4*)((const ushort_t*)W2v + base);
        *(u32x4*)&tile[row][c8] = v;
      } else {
        const float* src = (const float*)W2v + base;
        float4 w0 = *(const float4*)src;
        float4 w1 = *(const float4*)(src + 4);
        u32x4 pk;
        pk.x = packbf(w0.x, w0.y);
        pk.y = packbf(w0.z, w0.w);
        pk.z = packbf(w1.x, w1.y);
        pk.w = packbf(w1.z, w1.w);
        *(u32x4*)&tile[row][c8] = pk;
      }
    }
    __syncthreads();
#pragma unroll
    for (int i = 0; i < 2; ++i) {
      int nrow = i * 32 + r;
      union { ushort_t us[8]; u32x4 v; } pk;
#pragma unroll
      for (int jj = 0; jj < 8; ++jj) pk.us[jj] = tile[c8 + jj][nrow];
      *(u32x4*)(W2T + (size_t)(nt * 64 + nrow) * D1 + kt * 64 + c8) = pk.v;
    }
  } else if (bid < 2336) {
    // ================= M0/M1 fold =================
    const int k = (bid - 2304) * 256 + t;
    float m0 = 0.f, m1 = 0.f;
    if (isbf) {
      const ushort_t* Wspu = (const ushort_t*)W_spv;
      const ushort_t* W1u = (const ushort_t*)W1v;
      for (int e = 0; e < ED; ++e) {
        float w = bf2f(W1u[e * D1 + k]);
        m0 += bf2f(Wspu[e]) * w;
        m1 += bf2f(Wspu[ED + e]) * w;
      }
    } else {
      const float* Wspf = (const float*)W_spv;
      const float* W1f = (const float*)W1v;
      for (int e = 0; e < ED; ++e) {
        float w = W1f[e * D1 + k];
        m0 += Wspf[e] * w;
        m1 += Wspf[ED + e] * w;
      }
    }
    M0[k] = m0;
    M1[k] = m1;
  } else {
    // ================= epf / b2f / flag =================
    if (t == 0) *flag = isbf;
    const ushort_t* epu = (const ushort_t*)end_posv;
    const float* epff = (const float*)end_posv;
    const ushort_t* b2u = (const ushort_t*)b2v;
    const float* b2ff = (const float*)b2v;
    for (int i = t; i < 1024; i += 256) {
      epf[i] = isbf ? bf2f(epu[i]) : epff[i];
      b2f[i] = isbf ? bf2f(b2u[i]) : b2ff[i];
    }
  }
}

// ---------------------------------------------------------------------------
// k_gemm v3: 8-phase schedule (T3+T4+T5 on top of T2), m201-style.
// BM=256 BN=256 BK=64, 512 thr = 8 waves as 2M x 4N (wave tile 128m x 64n).
// Grid 256 = 1 block/CU. LDS: A[2][256][64] + B[2][256][64] = 128 KB.
// Iteration = 2 K-tiles = 8 phases. Per phase:
//   {4-8 ds_read_b128 subtile | stage ONE half-tile} barrier; lgkm0;
//   setprio(1); 16 MFMA; setprio(0); barrier.
// B halves staged via global_load_lds (2 loads/thr); A halves staged by fused
// generation (hv/M0/M1 loads issued one phase early; VALU + 2 ds_write/thr).
// vmcnt drains ONLY at phases 3/7 (__syncthreads) -> B loads span 2-3 phases.
// Both operands use XOR chunk swizzle slot = chunk ^ (row&7) (DMA-compatible).
// ---------------------------------------------------------------------------
#define BM 256
#define BN 256

__global__ __launch_bounds__(512, 2) void k_gemm(
    const ushort_t* __restrict__ hcb, const float* __restrict__ M0f,
    const float* __restrict__ M1f, const ushort_t* __restrict__ W2T,
    const float* __restrict__ epf, const float* __restrict__ b2f,
    const int* __restrict__ flag, void* __restrict__ outv) {
  __shared__ ushort_t aLds[2][BM * 64];  // 2 x 32 KB (rows 0-127 = half0)
  __shared__ ushort_t bLds[2][BN * 64];  // 2 x 32 KB (cols 0-127 = half0)
  __shared__ float2 rrLds[BM];

  const int t = threadIdx.x;
  const int w = t >> 6;
  const int lane = t & 63;

  // XCD-aware decode (grid 256 = 8 XCDs x 32 blocks)
  const int xcd = blockIdx.x & 7;
  const int idx = blockIdx.x >> 3;
  const int nb = xcd >> 1;                // N quarter (256 cols)
  const int mb = ((xcd & 1) << 5) | idx;  // 0..63 M tile (256 rows)
  const int s = mb >> 2;                  // scene
  const int a0 = (mb & 3) << 3;           // first of 8 a-values
  const int isbf = *flag;

  if (t < BM) {
    int al = t >> 5, b = t & 31;
    int pa = s * NPED + a0 + al, pb = s * NPED + b;
    float r0 = epf[pb * 2] - epf[pa * 2];
    float r1 = epf[pb * 2 + 1] - epf[pa * 2 + 1];
    rrLds[t] = make_float2(clip1(r0), clip1(r1));
  }
  __syncthreads();

  // ---- A-gen ids: thread (bq,kc) generates rows {i*64+bq} chunk kc ----
  const int bq = t >> 3;  // 0..63
  const int kc = t & 7;   // 0..7
  float rr0[4], rr1[4];   // row = i*64 + bq, i = h*2+g
#pragma unroll
  for (int i = 0; i < 4; ++i) {
    float2 v = rrLds[i * 64 + bq];
    rr0[i] = v.x;
    rr1[i] = v.y;
  }
  const ushort_t* hcRow = hcb + (size_t)(s * NPED + (bq & 31)) * D1 + kc * 8;
  const float* m0p = M0f + kc * 8;
  const float* m1p = M1f + kc * 8;
  const int aWoff = bq * 64 + (kc ^ (bq & 7)) * 8;  // + h*128*64 + g*64*64

  // ---- B DMA addressing: col_in_quarter = h*128 + i*64 + rowl ----
  const int rowl = w * 8 + (lane >> 3);
  const int chl = (lane & 7) ^ ((lane >> 3) & 7);  // fetch chunk = slot ^ (col&7)
  const ushort_t* bGlob = W2T + (size_t)(nb * BN + rowl) * D1 + chl * 8;
  ushort_t* bWr = &bLds[0][0] + rowl * 64 + (lane & 7) * 8;  // uniform + lane*16B

  // ---- MFMA fragment addressing ----
  const int wm = w >> 2;  // 0..1 -> A half
  const int wn = w & 3;   // 0..3 -> B half = wn>>1
  const int rl = lane & 15, q = lane >> 4, r7 = rl & 7;
  const int aRd = (wm * 128 + rl) * 64;  // + (mtg*64 + mt2*16)*64 + swz
  const int bRd = (wn * 64 + rl) * 64;   // + nt*16*64 + swz
  const int swz0 = (q ^ r7) * 8;         // ki=0: chunks 0..3
  const int swz1 = ((q + 4) ^ r7) * 8;   // ki=1: chunks 4..7

  f32x4 acc[8][4];
#pragma unroll
  for (int mt = 0; mt < 8; ++mt)
#pragma unroll
    for (int nt = 0; nt < 4; ++nt) acc[mt][nt] = (f32x4){0.f, 0.f, 0.f, 0.f};

  // A-gen staged operands (loaded one phase ahead of use)
  u32x4 hvn;
  float4 A0, A1, C0, C1;
  bf16x8 bfr[4];  // B frags, held across the two mtg-clusters of one ki

#define STAGE_B(bufsel, h, kt)                                              \
  do {                                                                      \
    const ushort_t* _s = bGlob + (size_t)(h) * 128 * D1 + (kt) * 64;        \
    ushort_t* _d = bWr + (bufsel) * (BN * 64) + (h) * 128 * 64;             \
    async_load16(_s, _d);                                                   \
    async_load16(_s + (size_t)64 * D1, _d + 64 * 64);                       \
  } while (0)

#define LOAD_HM(kt)                                                         \
  do {                                                                      \
    hvn = *(const u32x4*)(hcRow + (kt) * 64);                               \
    A0 = *(const float4*)(m0p + (kt) * 64);                                 \
    A1 = *(const float4*)(m0p + (kt) * 64 + 4);                             \
    C0 = *(const float4*)(m1p + (kt) * 64);                                 \
    C1 = *(const float4*)(m1p + (kt) * 64 + 4);                             \
  } while (0)

#define GEN_A(bufsel, h)                                                    \
  do {                                                                      \
    float h0, h1, h2, h3, h4, h5, h6, h7;                                   \
    unpk(hvn.x, h0, h1); unpk(hvn.y, h2, h3);                               \
    unpk(hvn.z, h4, h5); unpk(hvn.w, h6, h7);                               \
    ushort_t* _aw = &aLds[bufsel][0] + (h) * 128 * 64 + aWoff;              \
    _Pragma("unroll") for (int g = 0; g < 2; ++g) {                         \
      float r0 = rr0[(h) * 2 + g], r1 = rr1[(h) * 2 + g];                   \
      u32x4 pk;                                                             \
      pk.x = packbf(fmaxf(h0 + r0 * A0.x + r1 * C0.x, 0.f),                 \
                    fmaxf(h1 + r0 * A0.y + r1 * C0.y, 0.f));                \
      pk.y = packbf(fmaxf(h2 + r0 * A0.z + r1 * C0.z, 0.f),                 \
                    fmaxf(h3 + r0 * A0.w + r1 * C0.w, 0.f));                \
      pk.z = packbf(fmaxf(h4 + r0 * A1.x + r1 * C1.x, 0.f),                 \
                    fmaxf(h5 + r0 * A1.y + r1 * C1.y, 0.f));                \
      pk.w = packbf(fmaxf(h6 + r0 * A1.z + r1 * C1.z, 0.f),                 \
                    fmaxf(h7 + r0 * A1.w + r1 * C1.w, 0.f));                \
      *(u32x4*)(_aw + g * 64 * 64) = pk;                                    \
    }                                                                       \
  } while (0)

#define READ_BF(bufsel, sw)                                                 \
  do {                                                                      \
    const ushort_t* _bb = &bLds[bufsel][0];                                 \
    _Pragma("unroll") for (int nt = 0; nt < 4; ++nt)                        \
        bfr[nt] = *(const bf16x8*)(_bb + bRd + nt * 16 * 64 + (sw));        \
  } while (0)

#define READ_AF(bufsel, mtg, sw)                                            \
  do {                                                                      \
    const ushort_t* _ab = &aLds[bufsel][0];                                 \
    _Pragma("unroll") for (int m2 = 0; m2 < 4; ++m2)                        \
        af[m2] = *(const bf16x8*)(_ab + aRd + ((mtg) * 64 + m2 * 16) * 64 + \
                                  (sw));                                    \
  } while (0)

#define MFMA_CL(mtg)                                                        \
  do {                                                                      \
    __builtin_amdgcn_s_setprio(1);                                          \
    _Pragma("unroll") for (int m2 = 0; m2 < 4; ++m2)                        \
        _Pragma("unroll") for (int nt = 0; nt < 4; ++nt)                    \
            acc[(mtg) * 4 + m2][nt] =                                       \
        __builtin_amdgcn_mfma_f32_16x16x32_bf16(af[m2], bfr[nt],            \
                                                acc[(mtg) * 4 + m2][nt],    \
                                                0, 0, 0);                   \
    __builtin_amdgcn_s_setprio(0);                                          \
  } while (0)

#define LGKM0                                                               \
  asm volatile("s_waitcnt lgkmcnt(0)" ::: "memory");                        \
  __builtin_amdgcn_sched_barrier(0)
#define SBAR __builtin_amdgcn_s_barrier()

  // ================= prologue: tile 0 -> buf0 =================
  STAGE_B(0, 0, 0);
  STAGE_B(0, 1, 0);
  LOAD_HM(0);
  GEN_A(0, 0);
  GEN_A(0, 1);
  __syncthreads();  // drains prologue DMA + gen writes

  // ================= main loop: 64 iterations x 2 K-tiles =================
  for (int it = 0; it < 64; ++it) {
    const int ktn = 2 * it + 1;          // staged p0-3 into buf1, computed p4-7
    const int ktn2 = (2 * it + 2) & 127; // staged p4-7 into buf0 (wraps last it)
    bf16x8 af[4];

    // ---- p0: cluster (ki0,mtg0) | stage B h0 -> buf1 ----
    READ_BF(0, swz0);
    READ_AF(0, 0, swz0);
    STAGE_B(1, 0, ktn);
    SBAR; LGKM0;
    MFMA_CL(0);
    SBAR;
    // ---- p1: cluster (ki0,mtg1) | stage B h1 -> buf1 | prefetch hv/M ----
    READ_AF(0, 1, swz0);
    STAGE_B(1, 1, ktn);
    LOAD_HM(ktn);
    SBAR; LGKM0;
    MFMA_CL(1);
    SBAR;
    // ---- p2: cluster (ki1,mtg0) | gen A h0 -> buf1 ----
    READ_BF(0, swz1);
    READ_AF(0, 0, swz1);
    GEN_A(1, 0);
    LGKM0;  // drain gen writes (+ own reads) before barrier
    SBAR;
    MFMA_CL(0);
    SBAR;
    // ---- p3: cluster (ki1,mtg1) | gen A h1 -> buf1 | vmcnt drain ----
    READ_AF(0, 1, swz1);
    GEN_A(1, 1);
    __syncthreads();  // vmcnt(0)+lgkm(0)+barrier: buf1 fully staged
    MFMA_CL(1);
    SBAR;

    // ---- p4: tile ktn from buf1, cluster (ki0,mtg0) | stage B h0 -> buf0 ----
    READ_BF(1, swz0);
    READ_AF(1, 0, swz0);
    STAGE_B(0, 0, ktn2);
    SBAR; LGKM0;
    MFMA_CL(0);
    SBAR;
    // ---- p5 ----
    READ_AF(1, 1, swz0);
    STAGE_B(0, 1, ktn2);
    LOAD_HM(ktn2);
    SBAR; LGKM0;
    MFMA_CL(1);
    SBAR;
    // ---- p6 ----
    READ_BF(1, swz1);
    READ_AF(1, 0, swz1);
    GEN_A(0, 0);
    LGKM0;
    SBAR;
    MFMA_CL(0);
    SBAR;
    // ---- p7 ----
    READ_AF(1, 1, swz1);
    GEN_A(0, 1);
    __syncthreads();  // buf0 fully staged for next iteration
    MFMA_CL(1);
    SBAR;
  }

  // ---- epilogue: max over b, +b2, relu, store ----
  // acc[mt][nt] = C[wm*128 + mt*16 + q*4 + j][wn*64 + nt*16 + rl]
  // a_local = wm*4 + (mt>>1); b = (mt&1)*16 + q*4 + j.
#pragma unroll
  for (int g2 = 0; g2 < 4; ++g2) {
    int orow = s * NPED + a0 + wm * 4 + g2;
#pragma unroll
    for (int nt = 0; nt < 4; ++nt) {
      f32x4 x0 = acc[2 * g2][nt], x1 = acc[2 * g2 + 1][nt];
      float v = fmaxf(fmaxf(fmaxf(x0.x, x0.y), fmaxf(x0.z, x0.w)),
                      fmaxf(fmaxf(x1.x, x1.y), fmaxf(x1.z, x1.w)));
      v = fmaxf(v, __shfl_xor(v, 16, 64));
      v = fmaxf(v, __shfl_xor(v, 32, 64));
      if (lane < 16) {
        int col = nb * BN + wn * 64 + nt * 16 + lane;
        float o = fmaxf(v + b2f[col], 0.f);
        if (isbf)
          ((ushort_t*)outv)[(size_t)orow * BOTN + col] = f2bf(o);
        else
          ((float*)outv)[(size_t)orow * BOTN + col] = o;
      }
    }
  }
#undef STAGE_B
#undef LOAD_HM
#undef GEN_A
#undef READ_BF
#undef READ_AF
#undef MFMA_CL
#undef LGKM0
#undef SBAR
}

extern "C" void kernel_launch(void* const* d_in, const int* in_sizes, int n_in,
                              void* d_out, int out_size, void* d_ws, size_t ws_size,
                              hipStream_t stream) {
  (void)in_sizes; (void)n_in; (void)out_size; (void)ws_size;
  const void* h_states = d_in[0];
  const void* end_pos = d_in[1];
  // d_in[2] rel_pos: unused by reference; d_in[3] seq_start_end: fixed equal scenes
  const void* W_sp = d_in[4];
  const void* b_sp = d_in[5];
  const void* W1 = d_in[6];
  const void* b1 = d_in[7];
  const void* W2 = d_in[8];
  const void* b2 = d_in[9];

  char* ws = (char*)d_ws;
  ushort_t* hcb = (ushort_t*)ws;                         // 8 MB  (512x8192 bf16)
  ushort_t* W2T = (ushort_t*)(ws + (8u << 20));          // 16 MB (1024x8192 bf16)
  float* M0f = (float*)(ws + (24u << 20));               // 32 KB
  float* M1f = (float*)(ws + (24u << 20) + 32768);       // 32 KB
  float* epf = (float*)(ws + (24u << 20) + 98304);       // 4 KB
  float* b2f = (float*)(ws + (24u << 20) + 102400);      // 4 KB
  int* flag = (int*)(ws + (24u << 20) + 106496);         // 4 B

  k_pre<<<dim3(2337), dim3(256), 0, stream>>>(
      h_states, end_pos, W_sp, b_sp, W1, b1, W2, b2,
      flag, epf, b2f, M0f, M1f, hcb, W2T);
  k_gemm<<<dim3(256), dim3(512), 0, stream>>>(hcb, M0f, M1f, W2T, epf, b2f, flag, d_out);
}

// Round 4
// 442.017 us; speedup vs baseline: 1.0160x; 1.0160x over previous
//
#include <hip/hip_runtime.h>
#include <stdint.h>

#define NSCENE 16
#define NPED 32
#define HD 64
#define ED 64
#define D1 8192
#define BOTN 1024

typedef unsigned short ushort_t;
typedef __attribute__((ext_vector_type(4))) float f32x4;
typedef __attribute__((ext_vector_type(8))) __bf16 bf16x8;  // gfx950 mfma operand
typedef __attribute__((ext_vector_type(4))) unsigned int u32x4;
typedef __attribute__((ext_vector_type(2))) unsigned int u32x2;

__device__ __forceinline__ float bf2f(ushort_t u) {
  union { unsigned int i; float f; } x;
  x.i = ((unsigned int)u) << 16;
  return x.f;
}

__device__ __forceinline__ ushort_t f2bf(float f) {
  union { float f; unsigned int i; } x;
  x.f = f;
  unsigned int u = x.i + 0x7fffu + ((x.i >> 16) & 1u);
  return (ushort_t)(u >> 16);
}

// pack two f32 -> two bf16 RNE (lo in bits [15:0])
__device__ __forceinline__ unsigned int packbf(float lo, float hi) {
#if __has_builtin(__builtin_amdgcn_cvt_pk_bf16_f32)
  typedef __attribute__((ext_vector_type(2))) __bf16 bf16x2_t;
  union { bf16x2_t v; unsigned int u; } x;
  x.v = __builtin_amdgcn_cvt_pk_bf16_f32(lo, hi);
  return x.u;
#else
  return (unsigned int)f2bf(lo) | ((unsigned int)f2bf(hi) << 16);
#endif
}

// unpack u32 holding 2 bf16 -> 2 f32
__device__ __forceinline__ void unpk(unsigned int u, float& lo, float& hi) {
  union { unsigned int i; float f; } a, b;
  a.i = u << 16;
  b.i = u & 0xffff0000u;
  lo = a.f;
  hi = b.f;
}

__device__ __forceinline__ float clip1(float x) {
  return fminf(fmaxf(x, -1.f), 1.f);
}

// async global->LDS DMA, 16B/lane; LDS dest = wave-uniform base + lane*16.
__device__ __forceinline__ void async_load16(const void* g, void* l) {
  __builtin_amdgcn_global_load_lds(
      (const __attribute__((address_space(1))) unsigned int*)(unsigned long long)g,
      (__attribute__((address_space(3))) unsigned int*)(unsigned int)(unsigned long long)l,
      16, 0, 0);
}

// ---------------------------------------------------------------------------
// k_pre: ALL preprocessing in one kernel of independent blocks. (unchanged)
// ---------------------------------------------------------------------------
__global__ __launch_bounds__(256) void k_pre(
    const void* __restrict__ hv_, const void* __restrict__ end_posv,
    const void* __restrict__ W_spv, const void* __restrict__ b_spv,
    const void* __restrict__ W1v, const void* __restrict__ b1v,
    const void* __restrict__ W2v, const void* __restrict__ b2v,
    int* __restrict__ flag, float* __restrict__ epf, float* __restrict__ b2f,
    float* __restrict__ M0, float* __restrict__ M1,
    ushort_t* __restrict__ hcb, ushort_t* __restrict__ W2T) {
  __shared__ ushort_t tile[64][72];
  __shared__ int cnt[256];
  __shared__ int isbf_sh;
  const int t = threadIdx.x;
  const int bid = blockIdx.x;

  // ---- inline dtype detection ----
  {
    const ushort_t* wu = (const ushort_t*)W1v;
    unsigned int u = wu[2 * t];
    int e = (u >> 7) & 0xff;
    cnt[t] = (e >= 90 && e <= 140) ? 1 : 0;
    __syncthreads();
    for (int ofs = 128; ofs > 0; ofs >>= 1) {
      if (t < ofs) cnt[t] += cnt[t + ofs];
      __syncthreads();
    }
    if (t == 0) isbf_sh = (cnt[0] >= 128) ? 1 : 0;
    __syncthreads();
  }
  const int isbf = isbf_sh;

  if (bid < 256) {
    // ================= hc: hcb[j][k] = hbias[k] + h[j]@W1[64:] =============
    const int kb = bid & 7, jt = bid >> 3;
    const int kbase = kb * 1024 + t * 4;
    float hb0, hb1, hb2, hb3;
    if (isbf) {
      const ushort_t* b1u = (const ushort_t*)b1v;
      const ushort_t* bspu = (const ushort_t*)b_spv;
      const ushort_t* wp = (const ushort_t*)W1v + kbase;
      hb0 = bf2f(b1u[kbase]); hb1 = bf2f(b1u[kbase + 1]);
      hb2 = bf2f(b1u[kbase + 2]); hb3 = bf2f(b1u[kbase + 3]);
      for (int e = 0; e < ED; ++e) {
        float bs = bf2f(bspu[e]);
        u32x2 wv = *(const u32x2*)(wp + (size_t)e * D1);
        float w0, w1, w2, w3;
        unpk(wv.x, w0, w1); unpk(wv.y, w2, w3);
        hb0 += bs * w0; hb1 += bs * w1; hb2 += bs * w2; hb3 += bs * w3;
      }
    } else {
      const float* b1f = (const float*)b1v;
      const float* bspf = (const float*)b_spv;
      const float* wp = (const float*)W1v + kbase;
      hb0 = b1f[kbase]; hb1 = b1f[kbase + 1];
      hb2 = b1f[kbase + 2]; hb3 = b1f[kbase + 3];
      for (int e = 0; e < ED; ++e) {
        float bs = bspf[e];
        float4 w = *(const float4*)(wp + (size_t)e * D1);
        hb0 += bs * w.x; hb1 += bs * w.y; hb2 += bs * w.z; hb3 += bs * w.w;
      }
    }
    float acc[16][4];
#pragma unroll
    for (int j = 0; j < 16; ++j)
#pragma unroll
      for (int c = 0; c < 4; ++c) acc[j][c] = 0.f;
    if (isbf) {
      const ushort_t* wp = (const ushort_t*)W1v + (size_t)ED * D1 + kbase;
      const ushort_t* hp = (const ushort_t*)hv_ + jt * 16 * HD;
      for (int hh = 0; hh < HD; ++hh) {
        u32x2 wv = *(const u32x2*)(wp + (size_t)hh * D1);
        float w0, w1, w2, w3;
        unpk(wv.x, w0, w1); unpk(wv.y, w2, w3);
#pragma unroll
        for (int j = 0; j < 16; ++j) {
          float hj = bf2f(hp[j * HD + hh]);
          acc[j][0] += hj * w0;
          acc[j][1] += hj * w1;
          acc[j][2] += hj * w2;
          acc[j][3] += hj * w3;
        }
      }
    } else {
      const float* wp = (const float*)W1v + (size_t)ED * D1 + kbase;
      const float* hp = (const float*)hv_ + jt * 16 * HD;
#pragma unroll 4
      for (int hh = 0; hh < HD; ++hh) {
        float4 w = *(const float4*)(wp + (size_t)hh * D1);
#pragma unroll
        for (int j = 0; j < 16; ++j) {
          float hj = hp[j * HD + hh];
          acc[j][0] += hj * w.x;
          acc[j][1] += hj * w.y;
          acc[j][2] += hj * w.z;
          acc[j][3] += hj * w.w;
        }
      }
    }
#pragma unroll
    for (int j = 0; j < 16; ++j) {
      u32x2 pk;
      pk.x = packbf(acc[j][0] + hb0, acc[j][1] + hb1);
      pk.y = packbf(acc[j][2] + hb2, acc[j][3] + hb3);
      *(u32x2*)(hcb + (size_t)(jt * 16 + j) * D1 + kbase) = pk;
    }
  } else if (bid < 2304) {
    // ================= W2 transpose =================
    const int idx = bid - 256;
    const int kt = idx & 127, nt = idx >> 7;
    const int r = t >> 3, c8 = (t & 7) * 8;
#pragma unroll
    for (int i = 0; i < 2; ++i) {
      int row = i * 32 + r;
      size_t base = (size_t)(kt * 64 + row) * BOTN + nt * 64 + c8;
      if (isbf) {
        u32x4 v = *(const u32x4*)((const ushort_t*)W2v + base);
        *(u32x4*)&tile[row][c8] = v;
      } else {
        const float* src = (const float*)W2v + base;
        float4 w0 = *(const float4*)src;
        float4 w1 = *(const float4*)(src + 4);
        u32x4 pk;
        pk.x = packbf(w0.x, w0.y);
        pk.y = packbf(w0.z, w0.w);
        pk.z = packbf(w1.x, w1.y);
        pk.w = packbf(w1.z, w1.w);
        *(u32x4*)&tile[row][c8] = pk;
      }
    }
    __syncthreads();
#pragma unroll
    for (int i = 0; i < 2; ++i) {
      int nrow = i * 32 + r;
      union { ushort_t us[8]; u32x4 v; } pk;
#pragma unroll
      for (int jj = 0; jj < 8; ++jj) pk.us[jj] = tile[c8 + jj][nrow];
      *(u32x4*)(W2T + (size_t)(nt * 64 + nrow) * D1 + kt * 64 + c8) = pk.v;
    }
  } else if (bid < 2336) {
    // ================= M0/M1 fold =================
    const int k = (bid - 2304) * 256 + t;
    float m0 = 0.f, m1 = 0.f;
    if (isbf) {
      const ushort_t* Wspu = (const ushort_t*)W_spv;
      const ushort_t* W1u = (const ushort_t*)W1v;
      for (int e = 0; e < ED; ++e) {
        float w = bf2f(W1u[e * D1 + k]);
        m0 += bf2f(Wspu[e]) * w;
        m1 += bf2f(Wspu[ED + e]) * w;
      }
    } else {
      const float* Wspf = (const float*)W_spv;
      const float* W1f = (const float*)W1v;
      for (int e = 0; e < ED; ++e) {
        float w = W1f[e * D1 + k];
        m0 += Wspf[e] * w;
        m1 += Wspf[ED + e] * w;
      }
    }
    M0[k] = m0;
    M1[k] = m1;
  } else {
    // ================= epf / b2f / flag =================
    if (t == 0) *flag = isbf;
    const ushort_t* epu = (const ushort_t*)end_posv;
    const float* epff = (const float*)end_posv;
    const ushort_t* b2u = (const ushort_t*)b2v;
    const float* b2ff = (const float*)b2v;
    for (int i = t; i < 1024; i += 256) {
      epf[i] = isbf ? bf2f(epu[i]) : epff[i];
      b2f[i] = isbf ? bf2f(b2u[i]) : b2ff[i];
    }
  }
}

// ---------------------------------------------------------------------------
// k_gemm v4 (resubmit; R3 was an infra failure, not a kernel verdict).
// 8-phase schedule, register-lifetime-fixed (v3 spilled: VGPR=128 cap +
// WRITE_SIZE +3.5MB scratch).  Changes vs v3:
//  * hv/M0/M1 prefetch moved to phase C (1-phase hold), both A-halves
//    generated in phase D only -> no 3-phase live ranges, no spill.
//  * all extra lgkm/sched_barrier pins in write-phases removed; phase D's
//    __syncthreads provides the (once-per-K-tile) vmcnt+lgkm drain.
// Structure per K-tile (4 phases), iteration = 2 K-tiles = 8 phases:
//  A: read BF(ki0)+AF(mtg0) | stage B h0(next)   ; bar; lgkm0; 16 MFMA; bar
//  B: read AF(mtg1)         | stage B h1(next)   ; bar; lgkm0; 16 MFMA; bar
//  C: read BF(ki1)+AF(mtg0) | load hv/M(next)    ; bar; lgkm0; 16 MFMA; bar
//  D: read AF(mtg1)         | gen A both halves  ; __syncthreads; 16 MFMA; bar
// ---------------------------------------------------------------------------
#define BM 256
#define BN 256

__global__ __launch_bounds__(512, 2) void k_gemm(
    const ushort_t* __restrict__ hcb, const float* __restrict__ M0f,
    const float* __restrict__ M1f, const ushort_t* __restrict__ W2T,
    const float* __restrict__ epf, const float* __restrict__ b2f,
    const int* __restrict__ flag, void* __restrict__ outv) {
  __shared__ ushort_t aLds[2][BM * 64];  // 2 x 32 KB (rows 0-127 = half0)
  __shared__ ushort_t bLds[2][BN * 64];  // 2 x 32 KB (cols 0-127 = half0)
  __shared__ float2 rrLds[BM];

  const int t = threadIdx.x;
  const int w = t >> 6;
  const int lane = t & 63;

  // XCD-aware decode (grid 256 = 8 XCDs x 32 blocks)
  const int xcd = blockIdx.x & 7;
  const int idx = blockIdx.x >> 3;
  const int nb = xcd >> 1;                // N quarter (256 cols)
  const int mb = ((xcd & 1) << 5) | idx;  // 0..63 M tile (256 rows)
  const int s = mb >> 2;                  // scene
  const int a0 = (mb & 3) << 3;           // first of 8 a-values
  const int isbf = *flag;

  if (t < BM) {
    int al = t >> 5, b = t & 31;
    int pa = s * NPED + a0 + al, pb = s * NPED + b;
    float r0 = epf[pb * 2] - epf[pa * 2];
    float r1 = epf[pb * 2 + 1] - epf[pa * 2 + 1];
    rrLds[t] = make_float2(clip1(r0), clip1(r1));
  }
  __syncthreads();

  // ---- A-gen ids: thread (bq,kc) generates rows {i*64+bq} chunk kc ----
  const int bq = t >> 3;  // 0..63
  const int kc = t & 7;   // 0..7
  float rr0[4], rr1[4];   // row = i*64 + bq, i = h*2+g
#pragma unroll
  for (int i = 0; i < 4; ++i) {
    float2 v = rrLds[i * 64 + bq];
    rr0[i] = v.x;
    rr1[i] = v.y;
  }
  const ushort_t* hcRow = hcb + (size_t)(s * NPED + (bq & 31)) * D1 + kc * 8;
  const float* m0p = M0f + kc * 8;
  const float* m1p = M1f + kc * 8;
  const int aWoff = bq * 64 + (kc ^ (bq & 7)) * 8;  // + h*128*64 + g*64*64

  // ---- B DMA addressing: col_in_quarter = h*128 + i*64 + rowl ----
  const int rowl = w * 8 + (lane >> 3);
  const int chl = (lane & 7) ^ ((lane >> 3) & 7);  // fetch chunk = slot ^ (col&7)
  const ushort_t* bGlob = W2T + (size_t)(nb * BN + rowl) * D1 + chl * 8;
  ushort_t* bWr = &bLds[0][0] + rowl * 64 + (lane & 7) * 8;  // uniform + lane*16B

  // ---- MFMA fragment addressing ----
  const int wm = w >> 2;  // 0..1 -> A half
  const int wn = w & 3;   // 0..3 -> B half = wn>>1
  const int rl = lane & 15, q = lane >> 4, r7 = rl & 7;
  const int aRd = (wm * 128 + rl) * 64;  // + (mtg*64 + mt2*16)*64 + swz
  const int bRd = (wn * 64 + rl) * 64;   // + nt*16*64 + swz
  const int swz0 = (q ^ r7) * 8;         // ki=0: chunks 0..3
  const int swz1 = ((q + 4) ^ r7) * 8;   // ki=1: chunks 4..7

  f32x4 acc[8][4];
#pragma unroll
  for (int mt = 0; mt < 8; ++mt)
#pragma unroll
    for (int nt = 0; nt < 4; ++nt) acc[mt][nt] = (f32x4){0.f, 0.f, 0.f, 0.f};

  // A-gen staged operands (held ONE phase: C -> D)
  u32x4 hvn;
  float4 A0, A1, C0, C1;
  bf16x8 bfr[4];  // B frags, held across the two mtg-clusters of one ki
  bf16x8 af[4];

#define STAGE_B(bufsel, h, kt)                                              \
  do {                                                                      \
    const ushort_t* _s = bGlob + (size_t)(h) * 128 * D1 + (kt) * 64;        \
    ushort_t* _d = bWr + (bufsel) * (BN * 64) + (h) * 128 * 64;             \
    async_load16(_s, _d);                                                   \
    async_load16(_s + (size_t)64 * D1, _d + 64 * 64);                       \
  } while (0)

#define LOAD_HM(kt)                                                         \
  do {                                                                      \
    hvn = *(const u32x4*)(hcRow + (kt) * 64);                               \
    A0 = *(const float4*)(m0p + (kt) * 64);                                 \
    A1 = *(const float4*)(m0p + (kt) * 64 + 4);                             \
    C0 = *(const float4*)(m1p + (kt) * 64);                                 \
    C1 = *(const float4*)(m1p + (kt) * 64 + 4);                             \
  } while (0)

#define GEN_A(bufsel, h)                                                    \
  do {                                                                      \
    float h0, h1, h2, h3, h4, h5, h6, h7;                                   \
    unpk(hvn.x, h0, h1); unpk(hvn.y, h2, h3);                               \
    unpk(hvn.z, h4, h5); unpk(hvn.w, h6, h7);                               \
    ushort_t* _aw = &aLds[bufsel][0] + (h) * 128 * 64 + aWoff;              \
    _Pragma("unroll") for (int g = 0; g < 2; ++g) {                         \
      float r0 = rr0[(h) * 2 + g], r1 = rr1[(h) * 2 + g];                   \
      u32x4 pk;                                                             \
      pk.x = packbf(fmaxf(h0 + r0 * A0.x + r1 * C0.x, 0.f),                 \
                    fmaxf(h1 + r0 * A0.y + r1 * C0.y, 0.f));                \
      pk.y = packbf(fmaxf(h2 + r0 * A0.z + r1 * C0.z, 0.f),                 \
                    fmaxf(h3 + r0 * A0.w + r1 * C0.w, 0.f));                \
      pk.z = packbf(fmaxf(h4 + r0 * A1.x + r1 * C1.x, 0.f),                 \
                    fmaxf(h5 + r0 * A1.y + r1 * C1.y, 0.f));                \
      pk.w = packbf(fmaxf(h6 + r0 * A1.z + r1 * C1.z, 0.f),                 \
                    fmaxf(h7 + r0 * A1.w + r1 * C1.w, 0.f));                \
      *(u32x4*)(_aw + g * 64 * 64) = pk;                                    \
    }                                                                       \
  } while (0)

#define READ_BF(bufsel, sw)                                                 \
  do {                                                                      \
    const ushort_t* _bb = &bLds[bufsel][0];                                 \
    _Pragma("unroll") for (int nt = 0; nt < 4; ++nt)                        \
        bfr[nt] = *(const bf16x8*)(_bb + bRd + nt * 16 * 64 + (sw));        \
  } while (0)

#define READ_AF(bufsel, mtg, sw)                                            \
  do {                                                                      \
    const ushort_t* _ab = &aLds[bufsel][0];                                 \
    _Pragma("unroll") for (int m2 = 0; m2 < 4; ++m2)                        \
        af[m2] = *(const bf16x8*)(_ab + aRd + ((mtg) * 64 + m2 * 16) * 64 + \
                                  (sw));                                    \
  } while (0)

#define MFMA_CL(mtg)                                                        \
  do {                                                                      \
    __builtin_amdgcn_s_setprio(1);                                          \
    _Pragma("unroll") for (int m2 = 0; m2 < 4; ++m2)                        \
        _Pragma("unroll") for (int nt = 0; nt < 4; ++nt)                    \
            acc[(mtg) * 4 + m2][nt] =                                       \
        __builtin_amdgcn_mfma_f32_16x16x32_bf16(af[m2], bfr[nt],            \
                                                acc[(mtg) * 4 + m2][nt],    \
                                                0, 0, 0);                   \
    __builtin_amdgcn_s_setprio(0);                                          \
  } while (0)

#define LGKM0 asm volatile("s_waitcnt lgkmcnt(0)" ::: "memory")
#define SBAR __builtin_amdgcn_s_barrier()

  // ================= prologue: tile 0 -> buf0 =================
  STAGE_B(0, 0, 0);
  STAGE_B(0, 1, 0);
  LOAD_HM(0);
  GEN_A(0, 0);
  GEN_A(0, 1);
  __syncthreads();  // drains prologue DMA + gen writes

  // ================= main loop: 64 iterations x 2 K-tiles =================
  for (int it = 0; it < 64; ++it) {
    const int ktn = 2 * it + 1;          // staged in half1 (into buf1)
    const int ktn2 = (2 * it + 2) & 127; // staged in half2 (into buf0; wraps)

    // ======== half 1: compute buf0 (tile 2it), stage buf1 (tile ktn) ========
    // -- phase A --
    READ_BF(0, swz0);
    READ_AF(0, 0, swz0);
    STAGE_B(1, 0, ktn);
    SBAR; LGKM0;
    MFMA_CL(0);
    SBAR;
    // -- phase B --
    READ_AF(0, 1, swz0);
    STAGE_B(1, 1, ktn);
    SBAR; LGKM0;
    MFMA_CL(1);
    SBAR;
    // -- phase C --
    READ_BF(0, swz1);
    READ_AF(0, 0, swz1);
    LOAD_HM(ktn);
    SBAR; LGKM0;
    MFMA_CL(0);
    SBAR;
    // -- phase D --
    READ_AF(0, 1, swz1);
    GEN_A(1, 0);
    GEN_A(1, 1);
    __syncthreads();  // vmcnt+lgkm drain: buf1 fully staged
    MFMA_CL(1);
    SBAR;

    // ======== half 2: compute buf1 (tile ktn), stage buf0 (tile ktn2) ========
    // -- phase A --
    READ_BF(1, swz0);
    READ_AF(1, 0, swz0);
    STAGE_B(0, 0, ktn2);
    SBAR; LGKM0;
    MFMA_CL(0);
    SBAR;
    // -- phase B --
    READ_AF(1, 1, swz0);
    STAGE_B(0, 1, ktn2);
    SBAR; LGKM0;
    MFMA_CL(1);
    SBAR;
    // -- phase C --
    READ_BF(1, swz1);
    READ_AF(1, 0, swz1);
    LOAD_HM(ktn2);
    SBAR; LGKM0;
    MFMA_CL(0);
    SBAR;
    // -- phase D --
    READ_AF(1, 1, swz1);
    GEN_A(0, 0);
    GEN_A(0, 1);
    __syncthreads();  // buf0 fully staged for next iteration
    MFMA_CL(1);
    SBAR;
  }

  // ---- epilogue: max over b, +b2, relu, store ----
  // acc[mt][nt] = C[wm*128 + mt*16 + q*4 + j][wn*64 + nt*16 + rl]
  // a_local = wm*4 + (mt>>1); b = (mt&1)*16 + q*4 + j.
#pragma unroll
  for (int g2 = 0; g2 < 4; ++g2) {
    int orow = s * NPED + a0 + wm * 4 + g2;
#pragma unroll
    for (int nt = 0; nt < 4; ++nt) {
      f32x4 x0 = acc[2 * g2][nt], x1 = acc[2 * g2 + 1][nt];
      float v = fmaxf(fmaxf(fmaxf(x0.x, x0.y), fmaxf(x0.z, x0.w)),
                      fmaxf(fmaxf(x1.x, x1.y), fmaxf(x1.z, x1.w)));
      v = fmaxf(v, __shfl_xor(v, 16, 64));
      v = fmaxf(v, __shfl_xor(v, 32, 64));
      if (lane < 16) {
        int col = nb * BN + wn * 64 + nt * 16 + lane;
        float o = fmaxf(v + b2f[col], 0.f);
        if (isbf)
          ((ushort_t*)outv)[(size_t)orow * BOTN + col] = f2bf(o);
        else
          ((float*)outv)[(size_t)orow * BOTN + col] = o;
      }
    }
  }
#undef STAGE_B
#undef LOAD_HM
#undef GEN_A
#undef READ_BF
#undef READ_AF
#undef MFMA_CL
#undef LGKM0
#undef SBAR
}

extern "C" void kernel_launch(void* const* d_in, const int* in_sizes, int n_in,
                              void* d_out, int out_size, void* d_ws, size_t ws_size,
                              hipStream_t stream) {
  (void)in_sizes; (void)n_in; (void)out_size; (void)ws_size;
  const void* h_states = d_in[0];
  const void* end_pos = d_in[1];
  // d_in[2] rel_pos: unused by reference; d_in[3] seq_start_end: fixed equal scenes
  const void* W_sp = d_in[4];
  const void* b_sp = d_in[5];
  const void* W1 = d_in[6];
  const void* b1 = d_in[7];
  const void* W2 = d_in[8];
  const void* b2 = d_in[9];

  char* ws = (char*)d_ws;
  ushort_t* hcb = (ushort_t*)ws;                         // 8 MB  (512x8192 bf16)
  ushort_t* W2T = (ushort_t*)(ws + (8u << 20));          // 16 MB (1024x8192 bf16)
  float* M0f = (float*)(ws + (24u << 20));               // 32 KB
  float* M1f = (float*)(ws + (24u << 20) + 32768);       // 32 KB
  float* epf = (float*)(ws + (24u << 20) + 98304);       // 4 KB
  float* b2f = (float*)(ws + (24u << 20) + 102400);      // 4 KB
  int* flag = (int*)(ws + (24u << 20) + 106496);         // 4 B

  k_pre<<<dim3(2337), dim3(256), 0, stream>>>(
      h_states, end_pos, W_sp, b_sp, W1, b1, W2, b2,
      flag, epf, b2f, M0f, M1f, hcb, W2T);
  k_gemm<<<dim3(256), dim3(512), 0, stream>>>(hcb, M0f, M1f, W2T, epf, b2f, flag, d_out);
}